// Round 1
// baseline (5641.178 us; speedup 1.0000x reference)
//
#include <hip/hip_runtime.h>
#include <hip/hip_bf16.h>

#define TT 4
#define BB 16
#define VV 128
#define EE 512
#define HIDC 2048
#define BN_EPS 1e-5f

// ---------------- LIF over T (thread owns one (b,c,v) site) ----------------
__global__ __launch_bounds__(256) void lif_kernel(const float* __restrict__ in,
    float* __restrict__ out, int total, float vth)
{
  int i = blockIdx.x * 256 + threadIdx.x;
  if (i >= total) return;
  float v = 0.f;
#pragma unroll
  for (int t = 0; t < TT; ++t) {
    float x = in[(size_t)t * total + i];
    v += (x - v) * 0.5f;           // v = v + (x - v)/TAU, TAU=2
    float s = (v >= vth) ? 1.f : 0.f;
    out[(size_t)t * total + i] = s;
    v *= (1.f - s);                // hard reset
  }
}

// ---------------- patch embed: conv1x1 (CIN=2) + BN ----------------
__global__ __launch_bounds__(256) void pe_kernel(const float* __restrict__ x,
    const float* __restrict__ w, const float* __restrict__ bnp,
    float* __restrict__ h)
{
  int idx = blockIdx.x * 256 + threadIdx.x;       // T*B*E*V = 4194304
  int v = idx & 127;
  int o = (idx >> 7) & 511;
  int tb = idx >> 16;                             // t*B+b
  float x0 = x[((size_t)tb * 2 + 0) * VV + v];
  float x1 = x[((size_t)tb * 2 + 1) * VV + v];
  float a = w[o * 2 + 0] * x0 + w[o * 2 + 1] * x1;
  float g = bnp[o], be = bnp[EE + o], m = bnp[2 * EE + o], vr = bnp[3 * EE + o];
  float sc = g / sqrtf(vr + BN_EPS);
  h[idx] = (a - m) * sc + be;
}

// ---------------- fused conv1x1 (+bias) (+bn1) (+bn2) (+residual) ----------------
// In: [TB][C][V], W: [O][C], Out: [TB][O][V]
// grid: (TB, O/64), block 256. Each block: 64 o x 128 v tile.
__global__ __launch_bounds__(256) void gemm_bn(
    const float* __restrict__ In, const float* __restrict__ W,
    float* __restrict__ Out, const float* __restrict__ resid,
    const float* __restrict__ bias, const float* __restrict__ bn1,
    const float* __restrict__ bn2, int C, int O)
{
  const int tb = blockIdx.x;
  const int ob = blockIdx.y * 64;
  const int tid = threadIdx.x;
  __shared__ float sIn[32][128];
  __shared__ float sW[32][68];           // [c][o], pad 68 (bank spread, 16B-aligned rows)
  const int vp = (tid & 63) * 2;         // v pair
  const int og = (tid >> 6) * 16;        // wave-uniform o-group base
  float acc[16][2];
#pragma unroll
  for (int i = 0; i < 16; ++i) { acc[i][0] = 0.f; acc[i][1] = 0.f; }
  const float* inB = In + (size_t)tb * C * VV;

  for (int c0 = 0; c0 < C; c0 += 32) {
    // stage input tile 32x128 (coalesced float4)
#pragma unroll
    for (int i = 0; i < 4; ++i) {
      int idx = tid + i * 256;           // 0..1023 float4s
      int r = idx >> 5, col = (idx & 31) * 4;
      *(float4*)&sIn[r][col] = *(const float4*)&inB[(size_t)(c0 + r) * VV + col];
    }
    // stage W tile 64o x 32c, transposed into sW[c][o] (coalesced 128B reads)
#pragma unroll
    for (int i = 0; i < 2; ++i) {
      int idx = tid + i * 256;           // 0..511
      int o = idx >> 3, cq = (idx & 7) * 4;
      float4 wv = *(const float4*)&W[(size_t)(ob + o) * C + c0 + cq];
      sW[cq + 0][o] = wv.x; sW[cq + 1][o] = wv.y;
      sW[cq + 2][o] = wv.z; sW[cq + 3][o] = wv.w;
    }
    __syncthreads();
#pragma unroll 8
    for (int cc = 0; cc < 32; ++cc) {
      float2 iv = *(const float2*)&sIn[cc][vp];
      float4 w0 = *(const float4*)&sW[cc][og + 0];
      float4 w1 = *(const float4*)&sW[cc][og + 4];
      float4 w2 = *(const float4*)&sW[cc][og + 8];
      float4 w3 = *(const float4*)&sW[cc][og + 12];
      float ws[16] = {w0.x, w0.y, w0.z, w0.w, w1.x, w1.y, w1.z, w1.w,
                      w2.x, w2.y, w2.z, w2.w, w3.x, w3.y, w3.z, w3.w};
#pragma unroll
      for (int i = 0; i < 16; ++i) {
        acc[i][0] += ws[i] * iv.x;
        acc[i][1] += ws[i] * iv.y;
      }
    }
    __syncthreads();
  }

#pragma unroll
  for (int i = 0; i < 16; ++i) {
    int o = ob + og + i;
    float a0 = acc[i][0], a1 = acc[i][1];
    if (bias) { float bb = bias[o]; a0 += bb; a1 += bb; }
    if (bn1) {
      float g = bn1[o], be = bn1[O + o], m = bn1[2 * O + o], vr = bn1[3 * O + o];
      float sc = g / sqrtf(vr + BN_EPS);
      a0 = (a0 - m) * sc + be; a1 = (a1 - m) * sc + be;
    }
    if (bn2) {
      float g = bn2[o], be = bn2[O + o], m = bn2[2 * O + o], vr = bn2[3 * O + o];
      float sc = g / sqrtf(vr + BN_EPS);
      a0 = (a0 - m) * sc + be; a1 = (a1 - m) * sc + be;
    }
    size_t oi = ((size_t)tb * O + o) * VV + vp;
    if (resid) { a0 += resid[oi]; a1 += resid[oi + 1]; }
    Out[oi] = a0; Out[oi + 1] = a1;
  }
}

// ---------------- attention: KV[tbh][c][d] = sum_n K[c,n]*V[d,n] ----------------
__global__ __launch_bounds__(256) void attn_kv(const float* __restrict__ K,
    const float* __restrict__ Vv, float* __restrict__ KV)
{
  const int tbh = blockIdx.x;            // t*B*H + b*H + h
  const int tb = tbh >> 3, h = tbh & 7;
  const float* Kb = K + ((size_t)tb * EE + h * 64) * VV;
  const float* Vb = Vv + ((size_t)tb * EE + h * 64) * VV;
  __shared__ float sK[64][132], sV[64][132];
  const int tid = threadIdx.x;
#pragma unroll
  for (int i = 0; i < 8; ++i) {
    int idx = tid + i * 256;
    int r = idx >> 5, col = (idx & 31) * 4;
    *(float4*)&sK[r][col] = *(const float4*)&Kb[r * VV + col];
    *(float4*)&sV[r][col] = *(const float4*)&Vb[r * VV + col];
  }
  __syncthreads();
  const int cg = (tid >> 4) * 4;
  const int dg = (tid & 15) * 4;
  float acc[4][4] = {};
#pragma unroll 4
  for (int n = 0; n < 128; n += 4) {
    float4 ks[4], vs[4];
#pragma unroll
    for (int i = 0; i < 4; ++i) ks[i] = *(const float4*)&sK[cg + i][n];
#pragma unroll
    for (int j = 0; j < 4; ++j) vs[j] = *(const float4*)&sV[dg + j][n];
#pragma unroll
    for (int i = 0; i < 4; ++i)
#pragma unroll
      for (int j = 0; j < 4; ++j)
        acc[i][j] += ks[i].x * vs[j].x + ks[i].y * vs[j].y +
                     ks[i].z * vs[j].z + ks[i].w * vs[j].w;
  }
#pragma unroll
  for (int i = 0; i < 4; ++i)
#pragma unroll
    for (int j = 0; j < 4; ++j)
      KV[((size_t)tbh * 64 + cg + i) * 64 + dg + j] = acc[i][j];
}

// ---------------- attention: O[d,n] = 0.125 * sum_c KV[c][d]*Q[c,n] ----------------
__global__ __launch_bounds__(256) void attn_o(const float* __restrict__ Q,
    const float* __restrict__ KV, float* __restrict__ Out)
{
  const int tbh = blockIdx.x;
  const int tb = tbh >> 3, h = tbh & 7;
  const float* Qb = Q + ((size_t)tb * EE + h * 64) * VV;
  __shared__ float sQ[64][132];
  __shared__ float sKV[64][68];          // [c][d]
  const int tid = threadIdx.x;
#pragma unroll
  for (int i = 0; i < 8; ++i) {
    int idx = tid + i * 256;
    int r = idx >> 5, col = (idx & 31) * 4;
    *(float4*)&sQ[r][col] = *(const float4*)&Qb[r * VV + col];
  }
#pragma unroll
  for (int i = 0; i < 4; ++i) {
    int idx = tid + i * 256;             // 0..1023
    int c = idx >> 4, d4 = (idx & 15) * 4;
    float4 t = *(const float4*)&KV[(size_t)tbh * 4096 + c * 64 + d4];
    sKV[c][d4 + 0] = t.x; sKV[c][d4 + 1] = t.y;
    sKV[c][d4 + 2] = t.z; sKV[c][d4 + 3] = t.w;
  }
  __syncthreads();
  const int np = (tid & 63) * 2;
  const int dg = (tid >> 6) * 16;
  float acc[16][2] = {};
#pragma unroll 8
  for (int c = 0; c < 64; ++c) {
    float2 q2 = *(const float2*)&sQ[c][np];
    float4 w0 = *(const float4*)&sKV[c][dg + 0];
    float4 w1 = *(const float4*)&sKV[c][dg + 4];
    float4 w2 = *(const float4*)&sKV[c][dg + 8];
    float4 w3 = *(const float4*)&sKV[c][dg + 12];
    float ws[16] = {w0.x, w0.y, w0.z, w0.w, w1.x, w1.y, w1.z, w1.w,
                    w2.x, w2.y, w2.z, w2.w, w3.x, w3.y, w3.z, w3.w};
#pragma unroll
    for (int i = 0; i < 16; ++i) {
      acc[i][0] += ws[i] * q2.x;
      acc[i][1] += ws[i] * q2.y;
    }
  }
#pragma unroll
  for (int i = 0; i < 16; ++i) {
    size_t oi = ((size_t)tb * EE + h * 64 + dg + i) * VV + np;
    Out[oi] = acc[i][0] * 0.125f;
    Out[oi + 1] = acc[i][1] * 0.125f;
  }
}

// ---------------- head: mean over V ----------------
__global__ __launch_bounds__(256) void mean_v(const float* __restrict__ h,
    float* __restrict__ hm)
{
  int i = blockIdx.x * 256 + threadIdx.x;   // T*B*E = 32768
  const float* p = h + (size_t)i * VV;
  float s = 0.f;
#pragma unroll
  for (int v = 0; v < VV; v += 4) {
    float4 x = *(const float4*)&p[v];
    s += x.x + x.y + x.z + x.w;
  }
  hm[i] = s * (1.f / 128.f);
}

__global__ __launch_bounds__(256) void lif_head(const float* __restrict__ hm,
    float* __restrict__ sh)
{
  int i = blockIdx.x * 256 + threadIdx.x;   // B*E = 8192
  float v = 0.f;
#pragma unroll
  for (int t = 0; t < TT; ++t) {
    float x = hm[(size_t)t * (BB * EE) + i];
    v += (x - v) * 0.5f;
    float s = (v >= 1.f) ? 1.f : 0.f;
    sh[(size_t)t * (BB * EE) + i] = s;
    v *= (1.f - s);
  }
}

__global__ __launch_bounds__(256) void head_k(const float* __restrict__ sh,
    const float* __restrict__ hw, const float* __restrict__ hb,
    float* __restrict__ out)
{
  int i = threadIdx.x;
  if (i >= BB * 11) return;
  int b = i / 11, n = i % 11;
  float s = 0.f;
  for (int t = 0; t < TT; ++t) {
    const float* sp = sh + (size_t)t * (BB * EE) + b * EE;
    const float* wp = hw + n * EE;
    float ss = 0.f;
    for (int e = 0; e < EE; ++e) ss += sp[e] * wp[e];
    s += ss;
  }
  out[i] = s * 0.25f + hb[n];
}

// ---------------- launch ----------------
extern "C" void kernel_launch(void* const* d_in, const int* in_sizes, int n_in,
                              void* d_out, int out_size, void* d_ws, size_t ws_size,
                              hipStream_t stream) {
  const float* x       = (const float*)d_in[0];
  const float* pe_w    = (const float*)d_in[1];
  const float* pe_bn   = (const float*)d_in[2];
  const float* qkvp_w  = (const float*)d_in[3];
  const float* qkvp_bn = (const float*)d_in[4];
  const float* fc1_w   = (const float*)d_in[5];
  const float* fc1_b   = (const float*)d_in[6];
  const float* fc1_bn  = (const float*)d_in[7];
  const float* fc2_w   = (const float*)d_in[8];
  const float* fc2_b   = (const float*)d_in[9];
  const float* fc2_bn  = (const float*)d_in[10];
  const float* head_w  = (const float*)d_in[11];
  const float* head_b  = (const float*)d_in[12];
  float* out = (float*)d_out;

  const size_t NH = (size_t)TT * BB * EE * VV;   // 4194304
  float* ws    = (float*)d_ws;
  float* h     = ws;
  float* bufS  = h + NH;
  float* bufQ  = bufS + NH;
  float* bufK  = bufQ + NH;
  float* bufV  = bufK + NH;
  float* bufO  = bufV + NH;
  float* bufKV = bufO + NH;                      // 512*64*64 = 2097152
  float* bufHid = bufQ;                          // overlay: Q..KV span 18.9M >= 16.8M
  float* hm    = bufKV + (size_t)512 * 64 * 64;
  float* sh    = hm + TT * BB * EE;

  const int totE = BB * EE * VV;                 // 1048576
  const int totH = BB * HIDC * VV;               // 4194304

  pe_kernel<<<16384, 256, 0, stream>>>(x, pe_w, pe_bn, h);

  for (int d = 0; d < 6; ++d) {
    // ---- attention ----
    lif_kernel<<<totE / 256, 256, 0, stream>>>(h, bufS, totE, 1.f);
    float* dsts[3] = {bufQ, bufK, bufV};
    for (int i = 0; i < 3; ++i) {
      const float* w  = qkvp_w + ((size_t)(d * 4 + i)) * EE * EE;
      const float* b1 = qkvp_bn + ((size_t)((d * 4 + i) * 2 + 0)) * 4 * EE;
      const float* b2 = qkvp_bn + ((size_t)((d * 4 + i) * 2 + 1)) * 4 * EE;
      gemm_bn<<<dim3(64, 8), 256, 0, stream>>>(bufS, w, dsts[i], nullptr,
                                               nullptr, b1, b2, EE, EE);
      lif_kernel<<<totE / 256, 256, 0, stream>>>(dsts[i], dsts[i], totE, 1.f);
    }
    attn_kv<<<512, 256, 0, stream>>>(bufK, bufV, bufKV);
    attn_o<<<512, 256, 0, stream>>>(bufQ, bufKV, bufO);
    lif_kernel<<<totE / 256, 256, 0, stream>>>(bufO, bufO, totE, 0.5f);
    {
      const float* w  = qkvp_w + ((size_t)(d * 4 + 3)) * EE * EE;
      const float* b1 = qkvp_bn + ((size_t)((d * 4 + 3) * 2 + 0)) * 4 * EE;
      const float* b2 = qkvp_bn + ((size_t)((d * 4 + 3) * 2 + 1)) * 4 * EE;
      gemm_bn<<<dim3(64, 8), 256, 0, stream>>>(bufO, w, h, h,
                                               nullptr, b1, b2, EE, EE);
    }
    // ---- mlp ----
    lif_kernel<<<totE / 256, 256, 0, stream>>>(h, bufS, totE, 1.f);
    gemm_bn<<<dim3(64, 32), 256, 0, stream>>>(bufS, fc1_w + (size_t)d * HIDC * EE,
        bufHid, nullptr, fc1_b + (size_t)d * HIDC, fc1_bn + (size_t)d * 4 * HIDC,
        nullptr, EE, HIDC);
    lif_kernel<<<totH / 256, 256, 0, stream>>>(bufHid, bufHid, totH, 1.f);
    gemm_bn<<<dim3(64, 8), 256, 0, stream>>>(bufHid, fc2_w + (size_t)d * EE * HIDC,
        h, h, fc2_b + (size_t)d * EE, fc2_bn + (size_t)d * 4 * EE,
        nullptr, HIDC, EE);
  }

  mean_v<<<128, 256, 0, stream>>>(h, hm);
  lif_head<<<32, 256, 0, stream>>>(hm, sh);
  head_k<<<1, 256, 0, stream>>>(sh, head_w, head_b, out);
}

// Round 2
// 2076.924 us; speedup vs baseline: 2.7161x; 2.7161x over previous
//
#include <hip/hip_runtime.h>
#include <hip/hip_bf16.h>

#define TT 4
#define BB 16
#define VV 128
#define EE 512
#define HIDC 2048
#define BN_EPS 1e-5f

typedef unsigned int u32;

// ---------------- LIF over T (thread owns one site; grid.y selects buffer) ----------------
__global__ __launch_bounds__(256) void lif_kernel(const float* __restrict__ in,
    float* __restrict__ out, int total, float vth, long zstride)
{
  in  += (long)blockIdx.y * zstride;
  out += (long)blockIdx.y * zstride;
  int i = blockIdx.x * 256 + threadIdx.x;
  if (i >= total) return;
  float v = 0.f;
#pragma unroll
  for (int t = 0; t < TT; ++t) {
    float x = in[(size_t)t * total + i];
    v += (x - v) * 0.5f;           // v = v + (x - v)/TAU, TAU=2
    float s = (v >= vth) ? 1.f : 0.f;
    out[(size_t)t * total + i] = s;
    v *= (1.f - s);                // hard reset
  }
}

// ---------------- pack active-channel lists per (t,b) ----------------
// S: [TB][C][V] spike floats. lst: [TB][2048] u32 ascending channel ids. nact: [TB].
__global__ __launch_bounds__(256) void pack_act(const float* __restrict__ S,
    u32* __restrict__ lst, u32* __restrict__ nact, int C)
{
  const int tb = blockIdx.x, tid = threadIdx.x;
  __shared__ u32 words[64];
  if (tid < 64) words[tid] = 0;
  __syncthreads();
  const int wave = tid >> 6, lane = tid & 63, half = lane >> 5, l = lane & 31;
  const int pairs = C >> 1;
  for (int p = wave; p < pairs; p += 4) {
    int c = 2 * p + half;
    float4 x = *(const float4*)(S + ((size_t)tb * C + c) * VV + l * 4);
    bool f = (x.x != 0.f) || (x.y != 0.f) || (x.z != 0.f) || (x.w != 0.f);
    unsigned long long m = __ballot(f);
    u32 mm = half ? (u32)(m >> 32) : (u32)m;
    if (l == 0 && mm) atomicOr(&words[c >> 5], 1u << (c & 31));
  }
  __syncthreads();
  if (tid == 0) {
    int pos = 0;
    for (int w = 0; w < (C >> 5); ++w) {
      u32 m = words[w];
      while (m) { int b = __ffs(m) - 1; lst[(size_t)tb * 2048 + pos++] = w * 32 + b; m &= m - 1; }
    }
    nact[tb] = pos;
  }
}

// ---------------- per-layer weight transpose: WT[c][o] ----------------
__global__ __launch_bounds__(256) void trans6(const float* __restrict__ qw,
    const float* __restrict__ f1w, const float* __restrict__ f2w,
    float* __restrict__ wq, float* __restrict__ w1, float* __restrict__ w2)
{
  const int zz = blockIdx.y;
  const float* src; float* dst; int O, C;
  if (zz < 4)      { src = qw + (size_t)zz * EE * EE; dst = wq + (size_t)zz * EE * EE; O = EE;   C = EE; }
  else if (zz == 4){ src = f1w; dst = w1; O = HIDC; C = EE; }
  else             { src = f2w; dst = w2; O = EE;   C = HIDC; }
  const int tc_n = C >> 5, to_n = O >> 5;
  const int bx = blockIdx.x;
  if (bx >= tc_n * to_n) return;
  const int tc = bx % tc_n, to = bx / tc_n;
  __shared__ float t[32][33];
  const int tx = threadIdx.x & 31, ty = threadIdx.x >> 5;   // 32x8
#pragma unroll
  for (int k = 0; k < 4; ++k) {
    int o = to * 32 + ty + k * 8, c = tc * 32 + tx;
    t[ty + k * 8][tx] = src[(size_t)o * C + c];
  }
  __syncthreads();
#pragma unroll
  for (int k = 0; k < 4; ++k) {
    int c = tc * 32 + ty + k * 8, o = to * 32 + tx;
    dst[(size_t)c * O + o] = t[tx][ty + k * 8];
  }
}

// ---------------- patch embed: conv1x1 (CIN=2) + BN ----------------
__global__ __launch_bounds__(256) void pe_kernel(const float* __restrict__ x,
    const float* __restrict__ w, const float* __restrict__ bnp,
    float* __restrict__ h)
{
  int idx = blockIdx.x * 256 + threadIdx.x;       // T*B*E*V
  int v = idx & 127;
  int o = (idx >> 7) & 511;
  int tb = idx >> 16;
  float x0 = x[((size_t)tb * 2 + 0) * VV + v];
  float x1 = x[((size_t)tb * 2 + 1) * VV + v];
  float a = w[o * 2 + 0] * x0 + w[o * 2 + 1] * x1;
  float g = bnp[o], be = bnp[EE + o], m = bnp[2 * EE + o], vr = bnp[3 * EE + o];
  float sc = g / sqrtf(vr + BN_EPS);
  h[idx] = (a - m) * sc + be;
}

// ---------------- sparse spike GEMM + bias + bn1 + bn2 + residual ----------------
// In: [TB][C][V] spikes, WT: [C][O] (z-strided), Out: [TB][O][V] (z-strided)
// grid: (TB, O/64, nz), block 256. Tile: 64 o x 128 v; thread: 8 o x 4 v.
#define GEMM_FMA(cc)                                                         \
  {                                                                          \
    float4 iv = *(const float4*)&sIn[cc][vp];                                \
    float4 wa = *(const float4*)&sW[cc][og];                                 \
    float4 wb = *(const float4*)&sW[cc][og + 4];                             \
    float w8[8] = {wa.x, wa.y, wa.z, wa.w, wb.x, wb.y, wb.z, wb.w};          \
    _Pragma("unroll")                                                        \
    for (int j = 0; j < 8; ++j) {                                            \
      acc[j][0] += w8[j] * iv.x; acc[j][1] += w8[j] * iv.y;                  \
      acc[j][2] += w8[j] * iv.z; acc[j][3] += w8[j] * iv.w;                  \
    }                                                                        \
  }

__global__ __launch_bounds__(256) void gemm_sp(
    const float* __restrict__ In, const float* __restrict__ WT,
    float* __restrict__ Out, const float* __restrict__ resid,
    const float* __restrict__ bias, const float* __restrict__ bn1,
    const float* __restrict__ bn2, int C, int O,
    const u32* __restrict__ lst, const u32* __restrict__ nact,
    long wtZ, long outZ, long bnZ)
{
  const int tb = blockIdx.x, ob = blockIdx.y * 64, tid = threadIdx.x;
  const int z = blockIdx.z;
  WT += (long)z * wtZ; Out += (long)z * outZ;
  if (bn1) bn1 += (long)z * bnZ;
  if (bn2) bn2 += (long)z * bnZ;
  __shared__ float sIn[16][128];
  __shared__ float sW[16][64];
  const int og = (tid >> 5) * 8, vp = (tid & 31) * 4;
  float acc[8][4] = {};
  const int n = (int)nact[tb];
  const u32* L = lst + (size_t)tb * 2048;
  const float* inB = In + (size_t)tb * C * VV;

  int a0 = 0;
  while (a0 < n) {
    int m = n - a0; if (m > 16) m = 16;
    {
      int r0 = tid >> 5, q0 = (tid & 31) * 4;
      int r1 = r0 + 8;
      if (r0 < m) { int c = L[a0 + r0]; *(float4*)&sIn[r0][q0] = *(const float4*)&inB[(size_t)c * VV + q0]; }
      if (r1 < m) { int c = L[a0 + r1]; *(float4*)&sIn[r1][q0] = *(const float4*)&inB[(size_t)c * VV + q0]; }
      int rw = tid >> 4, ow = (tid & 15) * 4;
      if (rw < m) { int c = L[a0 + rw]; *(float4*)&sW[rw][ow] = *(const float4*)&WT[(size_t)c * O + ob + ow]; }
    }
    __syncthreads();
    if (m == 16) {
#pragma unroll
      for (int cc = 0; cc < 16; ++cc) GEMM_FMA(cc)
    } else {
      for (int cc = 0; cc < m; ++cc) GEMM_FMA(cc)
    }
    __syncthreads();
    a0 += 16;
  }

#pragma unroll
  for (int j = 0; j < 8; ++j) {
    int o = ob + og + j;
    float a0v = acc[j][0], a1v = acc[j][1], a2v = acc[j][2], a3v = acc[j][3];
    if (bias) { float bb = bias[o]; a0v += bb; a1v += bb; a2v += bb; a3v += bb; }
    if (bn1) {
      float g = bn1[o], be = bn1[O + o], m = bn1[2 * O + o], vr = bn1[3 * O + o];
      float sc = g / sqrtf(vr + BN_EPS);
      a0v = (a0v - m) * sc + be; a1v = (a1v - m) * sc + be;
      a2v = (a2v - m) * sc + be; a3v = (a3v - m) * sc + be;
    }
    if (bn2) {
      float g = bn2[o], be = bn2[O + o], m = bn2[2 * O + o], vr = bn2[3 * O + o];
      float sc = g / sqrtf(vr + BN_EPS);
      a0v = (a0v - m) * sc + be; a1v = (a1v - m) * sc + be;
      a2v = (a2v - m) * sc + be; a3v = (a3v - m) * sc + be;
    }
    size_t oi = ((size_t)tb * O + o) * VV + vp;
    if (resid) {
      float4 r = *(const float4*)&resid[oi];
      a0v += r.x; a1v += r.y; a2v += r.z; a3v += r.w;
    }
    float4 res = {a0v, a1v, a2v, a3v};
    *(float4*)&Out[oi] = res;
  }
}

// ---------------- attention: KV[tbh][c][d] = sum_n K[c,n]*V[d,n] ----------------
__global__ __launch_bounds__(256) void attn_kv(const float* __restrict__ K,
    const float* __restrict__ Vv, float* __restrict__ KV)
{
  const int tbh = blockIdx.x;
  const int tb = tbh >> 3, h = tbh & 7;
  const float* Kb = K + ((size_t)tb * EE + h * 64) * VV;
  const float* Vb = Vv + ((size_t)tb * EE + h * 64) * VV;
  __shared__ float sK[64][132], sV[64][132];
  const int tid = threadIdx.x;
#pragma unroll
  for (int i = 0; i < 8; ++i) {
    int idx = tid + i * 256;
    int r = idx >> 5, col = (idx & 31) * 4;
    *(float4*)&sK[r][col] = *(const float4*)&Kb[r * VV + col];
    *(float4*)&sV[r][col] = *(const float4*)&Vb[r * VV + col];
  }
  __syncthreads();
  const int cg = (tid >> 4) * 4;
  const int dg = (tid & 15) * 4;
  float acc[4][4] = {};
#pragma unroll 4
  for (int n = 0; n < 128; n += 4) {
    float4 ks[4], vs[4];
#pragma unroll
    for (int i = 0; i < 4; ++i) ks[i] = *(const float4*)&sK[cg + i][n];
#pragma unroll
    for (int j = 0; j < 4; ++j) vs[j] = *(const float4*)&sV[dg + j][n];
#pragma unroll
    for (int i = 0; i < 4; ++i)
#pragma unroll
      for (int j = 0; j < 4; ++j)
        acc[i][j] += ks[i].x * vs[j].x + ks[i].y * vs[j].y +
                     ks[i].z * vs[j].z + ks[i].w * vs[j].w;
  }
#pragma unroll
  for (int i = 0; i < 4; ++i)
#pragma unroll
    for (int j = 0; j < 4; ++j)
      KV[((size_t)tbh * 64 + cg + i) * 64 + dg + j] = acc[i][j];
}

// ---------------- attention: O[d,n] = 0.125 * sum_c KV[c][d]*Q[c,n] ----------------
__global__ __launch_bounds__(256) void attn_o(const float* __restrict__ Q,
    const float* __restrict__ KV, float* __restrict__ Out)
{
  const int tbh = blockIdx.x;
  const int tb = tbh >> 3, h = tbh & 7;
  const float* Qb = Q + ((size_t)tb * EE + h * 64) * VV;
  __shared__ float sQ[64][132];
  __shared__ float sKV[64][68];
  const int tid = threadIdx.x;
#pragma unroll
  for (int i = 0; i < 8; ++i) {
    int idx = tid + i * 256;
    int r = idx >> 5, col = (idx & 31) * 4;
    *(float4*)&sQ[r][col] = *(const float4*)&Qb[r * VV + col];
  }
#pragma unroll
  for (int i = 0; i < 4; ++i) {
    int idx = tid + i * 256;
    int c = idx >> 4, d4 = (idx & 15) * 4;
    float4 t = *(const float4*)&KV[(size_t)tbh * 4096 + c * 64 + d4];
    sKV[c][d4 + 0] = t.x; sKV[c][d4 + 1] = t.y;
    sKV[c][d4 + 2] = t.z; sKV[c][d4 + 3] = t.w;
  }
  __syncthreads();
  const int np = (tid & 63) * 2;
  const int dg = (tid >> 6) * 16;
  float acc[16][2] = {};
#pragma unroll 8
  for (int c = 0; c < 64; ++c) {
    float2 q2 = *(const float2*)&sQ[c][np];
    float4 w0 = *(const float4*)&sKV[c][dg + 0];
    float4 w1 = *(const float4*)&sKV[c][dg + 4];
    float4 w2 = *(const float4*)&sKV[c][dg + 8];
    float4 w3 = *(const float4*)&sKV[c][dg + 12];
    float ws[16] = {w0.x, w0.y, w0.z, w0.w, w1.x, w1.y, w1.z, w1.w,
                    w2.x, w2.y, w2.z, w2.w, w3.x, w3.y, w3.z, w3.w};
#pragma unroll
    for (int i = 0; i < 16; ++i) {
      acc[i][0] += ws[i] * q2.x;
      acc[i][1] += ws[i] * q2.y;
    }
  }
#pragma unroll
  for (int i = 0; i < 16; ++i) {
    size_t oi = ((size_t)tb * EE + h * 64 + dg + i) * VV + np;
    Out[oi] = acc[i][0] * 0.125f;
    Out[oi + 1] = acc[i][1] * 0.125f;
  }
}

// ---------------- head ----------------
__global__ __launch_bounds__(256) void mean_v(const float* __restrict__ h,
    float* __restrict__ hm)
{
  int i = blockIdx.x * 256 + threadIdx.x;   // T*B*E
  const float* p = h + (size_t)i * VV;
  float s = 0.f;
#pragma unroll
  for (int v = 0; v < VV; v += 4) {
    float4 x = *(const float4*)&p[v];
    s += x.x + x.y + x.z + x.w;
  }
  hm[i] = s * (1.f / 128.f);
}

__global__ __launch_bounds__(256) void lif_head(const float* __restrict__ hm,
    float* __restrict__ sh)
{
  int i = blockIdx.x * 256 + threadIdx.x;   // B*E
  float v = 0.f;
#pragma unroll
  for (int t = 0; t < TT; ++t) {
    float x = hm[(size_t)t * (BB * EE) + i];
    v += (x - v) * 0.5f;
    float s = (v >= 1.f) ? 1.f : 0.f;
    sh[(size_t)t * (BB * EE) + i] = s;
    v *= (1.f - s);
  }
}

__global__ __launch_bounds__(256) void head_k(const float* __restrict__ sh,
    const float* __restrict__ hw, const float* __restrict__ hb,
    float* __restrict__ out)
{
  int i = threadIdx.x;
  if (i >= BB * 11) return;
  int b = i / 11, n = i % 11;
  float s = 0.f;
  for (int t = 0; t < TT; ++t) {
    const float* sp = sh + (size_t)t * (BB * EE) + b * EE;
    const float* wp = hw + n * EE;
    float ss = 0.f;
    for (int e = 0; e < EE; ++e) ss += sp[e] * wp[e];
    s += ss;
  }
  out[i] = s * 0.25f + hb[n];
}

// ---------------- launch ----------------
extern "C" void kernel_launch(void* const* d_in, const int* in_sizes, int n_in,
                              void* d_out, int out_size, void* d_ws, size_t ws_size,
                              hipStream_t stream) {
  const float* x       = (const float*)d_in[0];
  const float* pe_w    = (const float*)d_in[1];
  const float* pe_bn   = (const float*)d_in[2];
  const float* qkvp_w  = (const float*)d_in[3];
  const float* qkvp_bn = (const float*)d_in[4];
  const float* fc1_w   = (const float*)d_in[5];
  const float* fc1_b   = (const float*)d_in[6];
  const float* fc1_bn  = (const float*)d_in[7];
  const float* fc2_w   = (const float*)d_in[8];
  const float* fc2_b   = (const float*)d_in[9];
  const float* fc2_bn  = (const float*)d_in[10];
  const float* head_w  = (const float*)d_in[11];
  const float* head_b  = (const float*)d_in[12];
  float* out = (float*)d_out;

  const size_t NH = (size_t)TT * BB * EE * VV;   // 4194304
  float* ws    = (float*)d_ws;
  float* h     = ws;
  float* bufS  = h + NH;
  float* bufQ  = bufS + NH;
  float* bufK  = bufQ + NH;
  float* bufV  = bufK + NH;
  float* bufO  = bufV + NH;
  float* bufKV = bufO + NH;                      // 2097152
  float* bufHid = bufQ;                          // overlay (Q..O span 4*NH)
  float* wtA   = bufKV + (size_t)512 * 64 * 64;  // 4*E*E
  float* wtF1  = wtA + (size_t)4 * EE * EE;      // HID*E
  float* wtF2  = wtF1 + (size_t)HIDC * EE;       // E*HID
  float* hm    = wtF2 + (size_t)EE * HIDC;
  float* sh    = hm + TT * BB * EE;
  u32*   lst   = (u32*)(sh + TT * BB * EE);      // 64*2048
  u32*   nact  = lst + (size_t)64 * 2048;

  const int totE = BB * EE * VV;                 // 1048576
  const int totH = BB * HIDC * VV;               // 4194304
  const int TBn = TT * BB;                       // 64

  pe_kernel<<<16384, 256, 0, stream>>>(x, pe_w, pe_bn, h);

  for (int d = 0; d < 6; ++d) {
    trans6<<<dim3(1024, 6), 256, 0, stream>>>(
        qkvp_w + (size_t)d * 4 * EE * EE,
        fc1_w + (size_t)d * HIDC * EE,
        fc2_w + (size_t)d * EE * HIDC, wtA, wtF1, wtF2);

    const float* bn1p = qkvp_bn + (size_t)d * 4 * 2 * 4 * EE;
    const float* bn2p = bn1p + 4 * EE;

    // ---- attention ----
    lif_kernel<<<dim3(totE / 256, 1), 256, 0, stream>>>(h, bufS, totE, 1.f, 0);
    pack_act<<<TBn, 256, 0, stream>>>(bufS, lst, nact, EE);
    gemm_sp<<<dim3(TBn, 8, 3), 256, 0, stream>>>(bufS, wtA, bufQ, nullptr,
        nullptr, bn1p, bn2p, EE, EE, lst, nact,
        (long)EE * EE, (long)NH, (long)2 * 4 * EE);
    lif_kernel<<<dim3(totE / 256, 3), 256, 0, stream>>>(bufQ, bufQ, totE, 1.f, (long)NH);
    attn_kv<<<512, 256, 0, stream>>>(bufK, bufV, bufKV);
    attn_o<<<512, 256, 0, stream>>>(bufQ, bufKV, bufO);
    lif_kernel<<<dim3(totE / 256, 1), 256, 0, stream>>>(bufO, bufO, totE, 0.5f, 0);
    pack_act<<<TBn, 256, 0, stream>>>(bufO, lst, nact, EE);
    gemm_sp<<<dim3(TBn, 8, 1), 256, 0, stream>>>(bufO, wtA + (size_t)3 * EE * EE,
        h, h, nullptr, bn1p + 3 * (2 * 4 * EE), bn2p + 3 * (2 * 4 * EE),
        EE, EE, lst, nact, 0, 0, 0);

    // ---- mlp ----
    lif_kernel<<<dim3(totE / 256, 1), 256, 0, stream>>>(h, bufS, totE, 1.f, 0);
    pack_act<<<TBn, 256, 0, stream>>>(bufS, lst, nact, EE);
    gemm_sp<<<dim3(TBn, 32, 1), 256, 0, stream>>>(bufS, wtF1, bufHid, nullptr,
        fc1_b + (size_t)d * HIDC, fc1_bn + (size_t)d * 4 * HIDC, nullptr,
        EE, HIDC, lst, nact, 0, 0, 0);
    lif_kernel<<<dim3(totH / 256, 1), 256, 0, stream>>>(bufHid, bufHid, totH, 1.f, 0);
    pack_act<<<TBn, 256, 0, stream>>>(bufHid, lst, nact, HIDC);
    gemm_sp<<<dim3(TBn, 8, 1), 256, 0, stream>>>(bufHid, wtF2, h, h,
        fc2_b + (size_t)d * EE, fc2_bn + (size_t)d * 4 * EE, nullptr,
        HIDC, EE, lst, nact, 0, 0, 0);
  }

  mean_v<<<128, 256, 0, stream>>>(h, hm);
  lif_head<<<32, 256, 0, stream>>>(hm, sh);
  head_k<<<1, 256, 0, stream>>>(sh, head_w, head_b, out);
}

// Round 3
// 1034.344 us; speedup vs baseline: 5.4539x; 2.0080x over previous
//
#include <hip/hip_runtime.h>
#include <hip/hip_bf16.h>

#define TT 4
#define BB 16
#define VV 128
#define EE 512
#define HIDC 2048
#define BN_EPS 1e-5f

typedef unsigned int u32;
typedef unsigned long long u64;
typedef unsigned char u8;

// ---------------- plain LIF (used for Q/K/V spikes; grid.y selects buffer) ----------------
__global__ __launch_bounds__(256) void lif_kernel(const float* __restrict__ in,
    float* __restrict__ out, int total, float vth, long zstride)
{
  in  += (long)blockIdx.y * zstride;
  out += (long)blockIdx.y * zstride;
  int i = blockIdx.x * 256 + threadIdx.x;
  if (i >= total) return;
  float v = 0.f;
#pragma unroll
  for (int t = 0; t < TT; ++t) {
    float x = in[(size_t)t * total + i];
    v += (x - v) * 0.5f;           // v = v + (x - v)/TAU, TAU=2
    float s = (v >= vth) ? 1.f : 0.f;
    out[(size_t)t * total + i] = s;
    v *= (1.f - s);                // hard reset
  }
}

// ---------------- LIF + per-channel activity flags ----------------
// One wave = one (b,c) channel; lane owns v=lane and v=lane+64.
// flags[(t*B+b)*C + c] = any spike in channel (byte, written every call).
__global__ __launch_bounds__(256) void lif_flags(const float* __restrict__ in,
    float* __restrict__ out, u8* __restrict__ flags, int C, int log2C, float vth)
{
  const int g = blockIdx.x * 4 + (threadIdx.x >> 6);
  const int lane = threadIdx.x & 63;
  const int b = g >> log2C, c = g & (C - 1);
  const size_t tot = (size_t)BB * C * VV;
  const size_t s0 = ((size_t)b * C + c) * VV + lane;
  float v0 = 0.f, v1 = 0.f;
#pragma unroll
  for (int t = 0; t < TT; ++t) {
    float x0 = in[(size_t)t * tot + s0];
    float x1 = in[(size_t)t * tot + s0 + 64];
    v0 += (x0 - v0) * 0.5f;
    v1 += (x1 - v1) * 0.5f;
    float sp0 = (v0 >= vth) ? 1.f : 0.f;
    float sp1 = (v1 >= vth) ? 1.f : 0.f;
    out[(size_t)t * tot + s0]      = sp0;
    out[(size_t)t * tot + s0 + 64] = sp1;
    v0 *= (1.f - sp0);
    v1 *= (1.f - sp1);
    u64 m = __ballot((sp0 != 0.f) || (sp1 != 0.f));
    if (lane == 0) flags[(size_t)(t * BB + b) * C + c] = m ? 1 : 0;
  }
}

// ---------------- flags -> ordered active-channel list per (t,b) ----------------
__global__ __launch_bounds__(256) void pack_list(const u8* __restrict__ flags,
    u32* __restrict__ lst, u32* __restrict__ nact, int C)
{
  const int tb = blockIdx.x, tid = threadIdx.x;
  const int lane = tid & 63, w = tid >> 6;
  __shared__ u32 wsum[4], woff[4], runb;
  if (tid == 0) runb = 0;
  __syncthreads();
  for (int c0 = 0; c0 < C; c0 += 256) {
    bool f = flags[(size_t)tb * C + c0 + tid] != 0;
    u64 m = __ballot(f);
    if (lane == 0) wsum[w] = __popcll(m);
    __syncthreads();
    if (tid == 0) {
      u32 s = runb;
#pragma unroll
      for (int k = 0; k < 4; ++k) { woff[k] = s; s += wsum[k]; }
      runb = s;
    }
    __syncthreads();
    if (f) {
      int rank = __popcll(m & ((1ull << lane) - 1));
      lst[(size_t)tb * 2048 + woff[w] + rank] = c0 + tid;
    }
    __syncthreads();
  }
  if (tid == 0) nact[tb] = runb;
}

// ---------------- per-layer weight transpose: WT[c][o] ----------------
__global__ __launch_bounds__(256) void trans6(const float* __restrict__ qw,
    const float* __restrict__ f1w, const float* __restrict__ f2w,
    float* __restrict__ wq, float* __restrict__ w1, float* __restrict__ w2)
{
  const int zz = blockIdx.y;
  const float* src; float* dst; int O, C;
  if (zz < 4)      { src = qw + (size_t)zz * EE * EE; dst = wq + (size_t)zz * EE * EE; O = EE;   C = EE; }
  else if (zz == 4){ src = f1w; dst = w1; O = HIDC; C = EE; }
  else             { src = f2w; dst = w2; O = EE;   C = HIDC; }
  const int tc_n = C >> 5, to_n = O >> 5;
  const int bx = blockIdx.x;
  if (bx >= tc_n * to_n) return;
  const int tc = bx % tc_n, to = bx / tc_n;
  __shared__ float t[32][33];
  const int tx = threadIdx.x & 31, ty = threadIdx.x >> 5;   // 32x8
#pragma unroll
  for (int k = 0; k < 4; ++k) {
    int o = to * 32 + ty + k * 8, c = tc * 32 + tx;
    t[ty + k * 8][tx] = src[(size_t)o * C + c];
  }
  __syncthreads();
#pragma unroll
  for (int k = 0; k < 4; ++k) {
    int c = tc * 32 + ty + k * 8, o = to * 32 + tx;
    dst[(size_t)c * O + o] = t[tx][ty + k * 8];
  }
}

// ---------------- patch embed: conv1x1 (CIN=2) + BN ----------------
__global__ __launch_bounds__(256) void pe_kernel(const float* __restrict__ x,
    const float* __restrict__ w, const float* __restrict__ bnp,
    float* __restrict__ h)
{
  int idx = blockIdx.x * 256 + threadIdx.x;       // T*B*E*V
  int v = idx & 127;
  int o = (idx >> 7) & 511;
  int tb = idx >> 16;
  float x0 = x[((size_t)tb * 2 + 0) * VV + v];
  float x1 = x[((size_t)tb * 2 + 1) * VV + v];
  float a = w[o * 2 + 0] * x0 + w[o * 2 + 1] * x1;
  float g = bnp[o], be = bnp[EE + o], m = bnp[2 * EE + o], vr = bnp[3 * EE + o];
  float sc = g / sqrtf(vr + BN_EPS);
  h[idx] = (a - m) * sc + be;
}

// ---------------- sparse spike GEMM + bias + bn1 + bn2 + residual ----------------
// In: [TB][C][V] spikes, WT: [C][O] (z-strided), Out: [TB][O][V] (z-strided)
// grid: (TB, O/64, nz), block 256. Tile: 64 o x 128 v; thread: 8 o x 4 v.
#define GEMM_FMA(cc)                                                         \
  {                                                                          \
    float4 iv = *(const float4*)&sIn[cc][vp];                                \
    float4 wa = *(const float4*)&sW[cc][og];                                 \
    float4 wb = *(const float4*)&sW[cc][og + 4];                             \
    float w8[8] = {wa.x, wa.y, wa.z, wa.w, wb.x, wb.y, wb.z, wb.w};          \
    _Pragma("unroll")                                                        \
    for (int j = 0; j < 8; ++j) {                                            \
      acc[j][0] += w8[j] * iv.x; acc[j][1] += w8[j] * iv.y;                  \
      acc[j][2] += w8[j] * iv.z; acc[j][3] += w8[j] * iv.w;                  \
    }                                                                        \
  }

__global__ __launch_bounds__(256) void gemm_sp(
    const float* __restrict__ In, const float* __restrict__ WT,
    float* __restrict__ Out, const float* __restrict__ resid,
    const float* __restrict__ bias, const float* __restrict__ bn1,
    const float* __restrict__ bn2, int C, int O,
    const u32* __restrict__ lst, const u32* __restrict__ nact,
    long wtZ, long outZ, long bnZ)
{
  const int tb = blockIdx.x, ob = blockIdx.y * 64, tid = threadIdx.x;
  const int z = blockIdx.z;
  WT += (long)z * wtZ; Out += (long)z * outZ;
  if (bn1) bn1 += (long)z * bnZ;
  if (bn2) bn2 += (long)z * bnZ;
  __shared__ float sIn[16][128];
  __shared__ float sW[16][64];
  const int og = (tid >> 5) * 8, vp = (tid & 31) * 4;
  float acc[8][4] = {};
  const int n = (int)nact[tb];
  const u32* L = lst + (size_t)tb * 2048;
  const float* inB = In + (size_t)tb * C * VV;

  int a0 = 0;
  while (a0 < n) {
    int m = n - a0; if (m > 16) m = 16;
    {
      int r0 = tid >> 5, q0 = (tid & 31) * 4;
      int r1 = r0 + 8;
      if (r0 < m) { int c = L[a0 + r0]; *(float4*)&sIn[r0][q0] = *(const float4*)&inB[(size_t)c * VV + q0]; }
      if (r1 < m) { int c = L[a0 + r1]; *(float4*)&sIn[r1][q0] = *(const float4*)&inB[(size_t)c * VV + q0]; }
      int rw = tid >> 4, ow = (tid & 15) * 4;
      if (rw < m) { int c = L[a0 + rw]; *(float4*)&sW[rw][ow] = *(const float4*)&WT[(size_t)c * O + ob + ow]; }
    }
    __syncthreads();
    if (m == 16) {
#pragma unroll
      for (int cc = 0; cc < 16; ++cc) GEMM_FMA(cc)
    } else {
      for (int cc = 0; cc < m; ++cc) GEMM_FMA(cc)
    }
    __syncthreads();
    a0 += 16;
  }

#pragma unroll
  for (int j = 0; j < 8; ++j) {
    int o = ob + og + j;
    float a0v = acc[j][0], a1v = acc[j][1], a2v = acc[j][2], a3v = acc[j][3];
    if (bias) { float bb = bias[o]; a0v += bb; a1v += bb; a2v += bb; a3v += bb; }
    if (bn1) {
      float g = bn1[o], be = bn1[O + o], m = bn1[2 * O + o], vr = bn1[3 * O + o];
      float sc = g / sqrtf(vr + BN_EPS);
      a0v = (a0v - m) * sc + be; a1v = (a1v - m) * sc + be;
      a2v = (a2v - m) * sc + be; a3v = (a3v - m) * sc + be;
    }
    if (bn2) {
      float g = bn2[o], be = bn2[O + o], m = bn2[2 * O + o], vr = bn2[3 * O + o];
      float sc = g / sqrtf(vr + BN_EPS);
      a0v = (a0v - m) * sc + be; a1v = (a1v - m) * sc + be;
      a2v = (a2v - m) * sc + be; a3v = (a3v - m) * sc + be;
    }
    size_t oi = ((size_t)tb * O + o) * VV + vp;
    if (resid) {
      float4 r = *(const float4*)&resid[oi];
      a0v += r.x; a1v += r.y; a2v += r.z; a3v += r.w;
    }
    float4 res = {a0v, a1v, a2v, a3v};
    *(float4*)&Out[oi] = res;
  }
}

// ---------------- attention: KV[tbh][c][d] = sum_n K[c,n]*V[d,n] ----------------
__global__ __launch_bounds__(256) void attn_kv(const float* __restrict__ K,
    const float* __restrict__ Vv, float* __restrict__ KV)
{
  const int tbh = blockIdx.x;
  const int tb = tbh >> 3, h = tbh & 7;
  const float* Kb = K + ((size_t)tb * EE + h * 64) * VV;
  const float* Vb = Vv + ((size_t)tb * EE + h * 64) * VV;
  __shared__ float sK[64][132], sV[64][132];
  const int tid = threadIdx.x;
#pragma unroll
  for (int i = 0; i < 8; ++i) {
    int idx = tid + i * 256;
    int r = idx >> 5, col = (idx & 31) * 4;
    *(float4*)&sK[r][col] = *(const float4*)&Kb[r * VV + col];
    *(float4*)&sV[r][col] = *(const float4*)&Vb[r * VV + col];
  }
  __syncthreads();
  const int cg = (tid >> 4) * 4;
  const int dg = (tid & 15) * 4;
  float acc[4][4] = {};
#pragma unroll 4
  for (int n = 0; n < 128; n += 4) {
    float4 ks[4], vs[4];
#pragma unroll
    for (int i = 0; i < 4; ++i) ks[i] = *(const float4*)&sK[cg + i][n];
#pragma unroll
    for (int j = 0; j < 4; ++j) vs[j] = *(const float4*)&sV[dg + j][n];
#pragma unroll
    for (int i = 0; i < 4; ++i)
#pragma unroll
      for (int j = 0; j < 4; ++j)
        acc[i][j] += ks[i].x * vs[j].x + ks[i].y * vs[j].y +
                     ks[i].z * vs[j].z + ks[i].w * vs[j].w;
  }
#pragma unroll
  for (int i = 0; i < 4; ++i)
#pragma unroll
    for (int j = 0; j < 4; ++j)
      KV[((size_t)tbh * 64 + cg + i) * 64 + dg + j] = acc[i][j];
}

// ---------------- attention: O[d,n] = 0.125 * sum_c KV[c][d]*Q[c,n] ----------------
__global__ __launch_bounds__(256) void attn_o(const float* __restrict__ Q,
    const float* __restrict__ KV, float* __restrict__ Out)
{
  const int tbh = blockIdx.x;
  const int tb = tbh >> 3, h = tbh & 7;
  const float* Qb = Q + ((size_t)tb * EE + h * 64) * VV;
  __shared__ float sQ[64][132];
  __shared__ float sKV[64][68];
  const int tid = threadIdx.x;
#pragma unroll
  for (int i = 0; i < 8; ++i) {
    int idx = tid + i * 256;
    int r = idx >> 5, col = (idx & 31) * 4;
    *(float4*)&sQ[r][col] = *(const float4*)&Qb[r * VV + col];
  }
#pragma unroll
  for (int i = 0; i < 4; ++i) {
    int idx = tid + i * 256;
    int c = idx >> 4, d4 = (idx & 15) * 4;
    float4 t = *(const float4*)&KV[(size_t)tbh * 4096 + c * 64 + d4];
    sKV[c][d4 + 0] = t.x; sKV[c][d4 + 1] = t.y;
    sKV[c][d4 + 2] = t.z; sKV[c][d4 + 3] = t.w;
  }
  __syncthreads();
  const int np = (tid & 63) * 2;
  const int dg = (tid >> 6) * 16;
  float acc[16][2] = {};
#pragma unroll 8
  for (int c = 0; c < 64; ++c) {
    float2 q2 = *(const float2*)&sQ[c][np];
    float4 w0 = *(const float4*)&sKV[c][dg + 0];
    float4 w1 = *(const float4*)&sKV[c][dg + 4];
    float4 w2 = *(const float4*)&sKV[c][dg + 8];
    float4 w3 = *(const float4*)&sKV[c][dg + 12];
    float ws[16] = {w0.x, w0.y, w0.z, w0.w, w1.x, w1.y, w1.z, w1.w,
                    w2.x, w2.y, w2.z, w2.w, w3.x, w3.y, w3.z, w3.w};
#pragma unroll
    for (int i = 0; i < 16; ++i) {
      acc[i][0] += ws[i] * q2.x;
      acc[i][1] += ws[i] * q2.y;
    }
  }
#pragma unroll
  for (int i = 0; i < 16; ++i) {
    size_t oi = ((size_t)tb * EE + h * 64 + dg + i) * VV + np;
    Out[oi] = acc[i][0] * 0.125f;
    Out[oi + 1] = acc[i][1] * 0.125f;
  }
}

// ---------------- head ----------------
__global__ __launch_bounds__(256) void mean_v(const float* __restrict__ h,
    float* __restrict__ hm)
{
  int i = blockIdx.x * 256 + threadIdx.x;   // T*B*E
  const float* p = h + (size_t)i * VV;
  float s = 0.f;
#pragma unroll
  for (int v = 0; v < VV; v += 4) {
    float4 x = *(const float4*)&p[v];
    s += x.x + x.y + x.z + x.w;
  }
  hm[i] = s * (1.f / 128.f);
}

__global__ __launch_bounds__(256) void lif_head(const float* __restrict__ hm,
    float* __restrict__ sh)
{
  int i = blockIdx.x * 256 + threadIdx.x;   // B*E
  float v = 0.f;
#pragma unroll
  for (int t = 0; t < TT; ++t) {
    float x = hm[(size_t)t * (BB * EE) + i];
    v += (x - v) * 0.5f;
    float s = (v >= 1.f) ? 1.f : 0.f;
    sh[(size_t)t * (BB * EE) + i] = s;
    v *= (1.f - s);
  }
}

__global__ __launch_bounds__(256) void head_k(const float* __restrict__ sh,
    const float* __restrict__ hw, const float* __restrict__ hb,
    float* __restrict__ out)
{
  int i = threadIdx.x;
  if (i >= BB * 11) return;
  int b = i / 11, n = i % 11;
  float s = 0.f;
  for (int t = 0; t < TT; ++t) {
    const float* sp = sh + (size_t)t * (BB * EE) + b * EE;
    const float* wp = hw + n * EE;
    float ss = 0.f;
    for (int e = 0; e < EE; ++e) ss += sp[e] * wp[e];
    s += ss;
  }
  out[i] = s * 0.25f + hb[n];
}

// ---------------- launch ----------------
extern "C" void kernel_launch(void* const* d_in, const int* in_sizes, int n_in,
                              void* d_out, int out_size, void* d_ws, size_t ws_size,
                              hipStream_t stream) {
  const float* x       = (const float*)d_in[0];
  const float* pe_w    = (const float*)d_in[1];
  const float* pe_bn   = (const float*)d_in[2];
  const float* qkvp_w  = (const float*)d_in[3];
  const float* qkvp_bn = (const float*)d_in[4];
  const float* fc1_w   = (const float*)d_in[5];
  const float* fc1_b   = (const float*)d_in[6];
  const float* fc1_bn  = (const float*)d_in[7];
  const float* fc2_w   = (const float*)d_in[8];
  const float* fc2_b   = (const float*)d_in[9];
  const float* fc2_bn  = (const float*)d_in[10];
  const float* head_w  = (const float*)d_in[11];
  const float* head_b  = (const float*)d_in[12];
  float* out = (float*)d_out;

  const size_t NH = (size_t)TT * BB * EE * VV;   // 4194304
  float* ws    = (float*)d_ws;
  float* h     = ws;
  float* bufS  = h + NH;
  float* bufQ  = bufS + NH;
  float* bufK  = bufQ + NH;
  float* bufV  = bufK + NH;
  float* bufO  = bufV + NH;
  float* bufKV = bufO + NH;                      // 2097152
  float* bufHid = bufQ;                          // overlay (Q..O span 4*NH)
  float* wtA   = bufKV + (size_t)512 * 64 * 64;  // 4*E*E
  float* wtF1  = wtA + (size_t)4 * EE * EE;      // HID*E
  float* wtF2  = wtF1 + (size_t)HIDC * EE;      // E*HID
  float* hm    = wtF2 + (size_t)EE * HIDC;
  float* sh    = hm + TT * BB * EE;
  u32*   lst   = (u32*)(sh + TT * BB * EE);      // 64*2048
  u32*   nact  = lst + (size_t)64 * 2048;
  u8*    flags = (u8*)(nact + 64);               // T*B*2048 bytes max

  const int totE = BB * EE * VV;                 // 1048576
  const int TBn = TT * BB;                       // 64

  pe_kernel<<<16384, 256, 0, stream>>>(x, pe_w, pe_bn, h);

  for (int d = 0; d < 6; ++d) {
    trans6<<<dim3(1024, 6), 256, 0, stream>>>(
        qkvp_w + (size_t)d * 4 * EE * EE,
        fc1_w + (size_t)d * HIDC * EE,
        fc2_w + (size_t)d * EE * HIDC, wtA, wtF1, wtF2);

    const float* bn1p = qkvp_bn + (size_t)d * 4 * 2 * 4 * EE;
    const float* bn2p = bn1p + 4 * EE;

    // ---- attention ----
    lif_flags<<<BB * EE / 4, 256, 0, stream>>>(h, bufS, flags, EE, 9, 1.f);
    pack_list<<<TBn, 256, 0, stream>>>(flags, lst, nact, EE);
    gemm_sp<<<dim3(TBn, 8, 3), 256, 0, stream>>>(bufS, wtA, bufQ, nullptr,
        nullptr, bn1p, bn2p, EE, EE, lst, nact,
        (long)EE * EE, (long)NH, (long)2 * 4 * EE);
    lif_kernel<<<dim3(totE / 256, 3), 256, 0, stream>>>(bufQ, bufQ, totE, 1.f, (long)NH);
    attn_kv<<<512, 256, 0, stream>>>(bufK, bufV, bufKV);
    attn_o<<<512, 256, 0, stream>>>(bufQ, bufKV, bufO);
    lif_flags<<<BB * EE / 4, 256, 0, stream>>>(bufO, bufO, flags, EE, 9, 0.5f);
    pack_list<<<TBn, 256, 0, stream>>>(flags, lst, nact, EE);
    gemm_sp<<<dim3(TBn, 8, 1), 256, 0, stream>>>(bufO, wtA + (size_t)3 * EE * EE,
        h, h, nullptr, bn1p + 3 * (2 * 4 * EE), bn2p + 3 * (2 * 4 * EE),
        EE, EE, lst, nact, 0, 0, 0);

    // ---- mlp ----
    lif_flags<<<BB * EE / 4, 256, 0, stream>>>(h, bufS, flags, EE, 9, 1.f);
    pack_list<<<TBn, 256, 0, stream>>>(flags, lst, nact, EE);
    gemm_sp<<<dim3(TBn, 32, 1), 256, 0, stream>>>(bufS, wtF1, bufHid, nullptr,
        fc1_b + (size_t)d * HIDC, fc1_bn + (size_t)d * 4 * HIDC, nullptr,
        EE, HIDC, lst, nact, 0, 0, 0);
    lif_flags<<<BB * HIDC / 4, 256, 0, stream>>>(bufHid, bufHid, flags, HIDC, 11, 1.f);
    pack_list<<<TBn, 256, 0, stream>>>(flags, lst, nact, HIDC);
    gemm_sp<<<dim3(TBn, 8, 1), 256, 0, stream>>>(bufHid, wtF2, h, h,
        fc2_b + (size_t)d * EE, fc2_bn + (size_t)d * 4 * EE, nullptr,
        HIDC, EE, lst, nact, 0, 0, 0);
  }

  mean_v<<<128, 256, 0, stream>>>(h, hm);
  lif_head<<<32, 256, 0, stream>>>(hm, sh);
  head_k<<<1, 256, 0, stream>>>(sh, head_w, head_b, out);
}